// Round 3
// baseline (66.848 us; speedup 1.0000x reference)
//
#include <hip/hip_runtime.h>

// out[m, n] = sum_d a[m, d] * T_d(x[n]),  T_d = Chebyshev via recurrence.
// N = 2097152, M = 32, DEG = 16. Write-BW-bound (~256 MiB out, write-once).
// R2: nontemporal stores via native clang vector type (HIP_vector_type is a
// class and __builtin_nontemporal_* rejects it).

#define DEG 16
#define M_ROWS 32
#define ELEMS_PER_THREAD 4

typedef __attribute__((ext_vector_type(4))) float f32x4;

__global__ __launch_bounds__(256) void cheb_gemm_kernel(
    const float* __restrict__ x,
    const float* __restrict__ a,
    float* __restrict__ out,
    int n)
{
    const int i = (blockIdx.x * 256 + threadIdx.x) * ELEMS_PER_THREAD;
    if (i + ELEMS_PER_THREAD - 1 >= n) return;

    // Coalesced 16B load of 4 consecutive x values (read-once -> nontemporal).
    const f32x4 xv = __builtin_nontemporal_load(
        reinterpret_cast<const f32x4*>(x + i));
    float xs[ELEMS_PER_THREAD] = {xv.x, xv.y, xv.z, xv.w};

    // Chebyshev basis T_0..T_15 for each of the 4 elements, in registers.
    float basis[ELEMS_PER_THREAD][DEG];
#pragma unroll
    for (int j = 0; j < ELEMS_PER_THREAD; ++j) {
        float t0 = 1.0f;
        float t1 = xs[j];
        basis[j][0] = t0;
        basis[j][1] = t1;
        const float two_x = xs[j] + xs[j];
#pragma unroll
        for (int k = 2; k < DEG; ++k) {
            float t2 = fmaf(two_x, t1, -t0);
            basis[j][k] = t2;
            t0 = t1;
            t1 = t2;
        }
    }

    // For each output row m: dot(a[m, :], basis[j, :]) then float4 nt-store.
    // a[] addresses are wave-uniform -> scalar loads (s_load_dwordx16 per row).
#pragma unroll 4
    for (int m = 0; m < M_ROWS; ++m) {
        float acc0 = 0.0f, acc1 = 0.0f, acc2 = 0.0f, acc3 = 0.0f;
#pragma unroll
        for (int d = 0; d < DEG; ++d) {
            const float c = a[m * DEG + d];
            acc0 = fmaf(c, basis[0][d], acc0);
            acc1 = fmaf(c, basis[1][d], acc1);
            acc2 = fmaf(c, basis[2][d], acc2);
            acc3 = fmaf(c, basis[3][d], acc3);
        }
        f32x4 v;
        v.x = acc0; v.y = acc1; v.z = acc2; v.w = acc3;
        __builtin_nontemporal_store(
            v, reinterpret_cast<f32x4*>(out + (size_t)m * (size_t)n + i));
    }
}

extern "C" void kernel_launch(void* const* d_in, const int* in_sizes, int n_in,
                              void* d_out, int out_size, void* d_ws, size_t ws_size,
                              hipStream_t stream) {
    const float* x = (const float*)d_in[0];
    const float* a = (const float*)d_in[1];
    float* out = (float*)d_out;
    const int n = in_sizes[0];  // 2097152

    const int threads = 256;
    const int elems_per_block = threads * ELEMS_PER_THREAD;  // 1024
    const int blocks = (n + elems_per_block - 1) / elems_per_block;  // 2048

    cheb_gemm_kernel<<<blocks, threads, 0, stream>>>(x, a, out, n);
}

// Round 4
// 66.686 us; speedup vs baseline: 1.0024x; 1.0024x over previous
//
#include <hip/hip_runtime.h>

// out[m, n] = sum_d a[m, d] * T_d(x[n]),  T_d = Chebyshev via recurrence.
// N = 2097152, M = 32, DEG = 16. Write-BW-bound (~256 MiB out, write-once).
// R3: one block = one (m, n-chunk) tile -> each block writes ONE contiguous
// 4 KB region (fill-kernel-like stream behavior) instead of every thread
// scattering across 32 streams at 8 MB stride. Basis recomputed per m
// (VALU ~25 us total, hidden under ~40 us store drain). x re-reads hit L2/LLC.
// NT stores REVERTED: R2 showed they cost +15 us (L2 write-combining matters).

#define DEG 16
#define M_ROWS 32
#define ELEMS_PER_THREAD 4

__global__ __launch_bounds__(256) void cheb_gemm_kernel(
    const float* __restrict__ x,
    const float* __restrict__ a,
    float* __restrict__ out,
    int n)
{
    // n-major block order: 32 consecutive blocks share the same x chunk (L2 hit)
    const int b = blockIdx.x;
    const int m = b & (M_ROWS - 1);
    const int chunk = b >> 5;
    const int i = chunk * (256 * ELEMS_PER_THREAD) + threadIdx.x * ELEMS_PER_THREAD;
    if (i + ELEMS_PER_THREAD - 1 >= n) return;

    // Coalesced 16B load of 4 consecutive x values.
    const float4 xv = *reinterpret_cast<const float4*>(x + i);
    const float xs[ELEMS_PER_THREAD] = {xv.x, xv.y, xv.z, xv.w};

    // Coefficients for this block's m-row: wave-uniform -> scalar loads.
    float c[DEG];
#pragma unroll
    for (int d = 0; d < DEG; ++d) c[d] = a[m * DEG + d];

    // Chebyshev recurrence fused with the dot product: T0=1, T1=x,
    // T_k = 2x*T_{k-1} - T_{k-2}; acc += c[k]*T_k.
    float acc[ELEMS_PER_THREAD];
#pragma unroll
    for (int j = 0; j < ELEMS_PER_THREAD; ++j) {
        float t0 = 1.0f;
        float t1 = xs[j];
        const float two_x = xs[j] + xs[j];
        float s = fmaf(c[1], t1, c[0]);
#pragma unroll
        for (int k = 2; k < DEG; ++k) {
            const float t2 = fmaf(two_x, t1, -t0);
            s = fmaf(c[k], t2, s);
            t0 = t1;
            t1 = t2;
        }
        acc[j] = s;
    }

    // Single contiguous 16B store; block writes one 4 KB region of row m.
    float4* dst = reinterpret_cast<float4*>(out + (size_t)m * (size_t)n + i);
    *dst = make_float4(acc[0], acc[1], acc[2], acc[3]);
}

extern "C" void kernel_launch(void* const* d_in, const int* in_sizes, int n_in,
                              void* d_out, int out_size, void* d_ws, size_t ws_size,
                              hipStream_t stream) {
    const float* x = (const float*)d_in[0];
    const float* a = (const float*)d_in[1];
    float* out = (float*)d_out;
    const int n = in_sizes[0];  // 2097152

    const int threads = 256;
    const int elems_per_block = threads * ELEMS_PER_THREAD;       // 1024
    const int chunks = (n + elems_per_block - 1) / elems_per_block;  // 2048
    const int blocks = chunks * M_ROWS;                           // 65536

    cheb_gemm_kernel<<<blocks, threads, 0, stream>>>(x, a, out, n);
}

// Round 5
// 56.946 us; speedup vs baseline: 1.1739x; 1.1710x over previous
//
#include <hip/hip_runtime.h>

// out[m, n] = sum_d a[m, d] * T_d(x[n]),  T_d = Chebyshev via recurrence.
// N = 2097152, M = 32, DEG = 16. Write-BW-bound (~256 MiB out).
// R4: back to R0's amortized-basis structure (R3's per-m recompute doubled
// VALU; NT stores hurt). Two changes vs R0, one theory (compute overlap):
//  - EPT=2: basis regs 64->32 floats, ~50 VGPR, __launch_bounds__(256,8)
//    -> 8 waves/SIMD (R0's ~90 VGPR capped us at 4).
//  - v_pk_fma_f32 over d-pairs: coeff pair is a wave-uniform SGPR64 src,
//    basis pairs in VGPR pairs. Halves dot-product VALU insts.

#define DEG 16
#define M_ROWS 32
#define EPT 2

typedef __attribute__((ext_vector_type(2))) float f32x2;

__global__ __launch_bounds__(256, 8) void cheb_gemm_kernel(
    const float* __restrict__ x,
    const float* __restrict__ a,
    float* __restrict__ out,
    int n)
{
    const int i = (blockIdx.x * 256 + threadIdx.x) * EPT;
    if (i + EPT - 1 >= n) return;

    const float2 xv = *reinterpret_cast<const float2*>(x + i);
    const float xs[EPT] = {xv.x, xv.y};

    // Basis pairs bp[j][dd] = {T_{2dd}(x_j), T_{2dd+1}(x_j)} via recurrence.
    f32x2 bp[EPT][DEG / 2];
#pragma unroll
    for (int j = 0; j < EPT; ++j) {
        float t0 = 1.0f;
        float t1 = xs[j];
        const float two_x = xs[j] + xs[j];
        bp[j][0].x = t0;
        bp[j][0].y = t1;
#pragma unroll
        for (int k = 2; k < DEG; ++k) {
            const float t2 = fmaf(two_x, t1, -t0);
            if (k & 1) bp[j][k >> 1].y = t2;
            else       bp[j][k >> 1].x = t2;
            t0 = t1;
            t1 = t2;
        }
    }

    // Per m-row: packed dot product. acc holds {even-d partial, odd-d partial}.
#pragma unroll 4
    for (int m = 0; m < M_ROWS; ++m) {
        const float* am = a + m * DEG;
        f32x2 acc0, acc1;
        {
            const f32x2 cp = *reinterpret_cast<const f32x2*>(am);
            asm("v_pk_mul_f32 %0, %1, %2" : "=v"(acc0) : "s"(cp), "v"(bp[0][0]));
            asm("v_pk_mul_f32 %0, %1, %2" : "=v"(acc1) : "s"(cp), "v"(bp[1][0]));
        }
#pragma unroll
        for (int dd = 1; dd < DEG / 2; ++dd) {
            const f32x2 cp = *reinterpret_cast<const f32x2*>(am + 2 * dd);
            asm("v_pk_fma_f32 %0, %1, %2, %0" : "+v"(acc0) : "s"(cp), "v"(bp[0][dd]));
            asm("v_pk_fma_f32 %0, %1, %2, %0" : "+v"(acc1) : "s"(cp), "v"(bp[1][dd]));
        }
        float2* dst = reinterpret_cast<float2*>(out + (size_t)m * (size_t)n + i);
        *dst = make_float2(acc0.x + acc0.y, acc1.x + acc1.y);
    }
}

extern "C" void kernel_launch(void* const* d_in, const int* in_sizes, int n_in,
                              void* d_out, int out_size, void* d_ws, size_t ws_size,
                              hipStream_t stream) {
    const float* x = (const float*)d_in[0];
    const float* a = (const float*)d_in[1];
    float* out = (float*)d_out;
    const int n = in_sizes[0];  // 2097152

    const int threads = 256;
    const int elems_per_block = threads * EPT;                 // 512
    const int blocks = (n + elems_per_block - 1) / elems_per_block;  // 4096

    cheb_gemm_kernel<<<blocks, threads, 0, stream>>>(x, a, out, n);
}